// Round 8
// baseline (130.460 us; speedup 1.0000x reference)
//
#include <hip/hip_runtime.h>

#define IN_DIM 256
#define OUT_DIM 128
#define SLOPE 0.1f
#define CAP 128   // per-dst bucket capacity; degree ~ Poisson(33), max ~70

typedef short bf16x8 __attribute__((ext_vector_type(8)));
typedef float f32x4  __attribute__((ext_vector_type(4)));

__device__ __forceinline__ unsigned short f2bf(float f) {
    unsigned u = __builtin_bit_cast(unsigned, f);
    return (unsigned short)((u + 0x7FFFu + ((u >> 16) & 1u)) >> 16);   // RNE
}

// ---------------------------------------------------------------------------
// Kernel 1: emb = feats @ W^T + b via bf16 MFMA. BM=64 tile (782 blocks,
// 3 blocks/CU -> balanced grid). Fused: s_dst/s_src scores, cur[]=0 init.
// Epilogue: acc -> LDS transpose (stride 136 = conflict-free) -> coalesced
// 16B bf16 stores (replaces 64 scalar ushort stores/thread).
// ---------------------------------------------------------------------------
__global__ __launch_bounds__(256) void gemm_mfma_kernel(
    const float* __restrict__ feats, const float* __restrict__ W,
    const float* __restrict__ bias, const float* __restrict__ a,
    unsigned short* __restrict__ emb_bf, float* __restrict__ s_dst,
    float* __restrict__ s_src, int* __restrict__ cur, int n)
{
    __shared__ __align__(16) unsigned short A_s[64 * 136];   // staging(64x128) + transpose(64x136)
    __shared__ __align__(16) unsigned short W_s[128 * 128];
    __shared__ float sd_l[2][64];
    __shared__ float ss_l[2][64];

    const int t    = threadIdx.x;
    const int lane = t & 63;
    const int wid  = t >> 6;
    const int wr   = wid >> 1;          // 0..1 : 32-row half
    const int wc   = wid & 1;           // 0..1 : 64-col half
    const int row0 = blockIdx.x * 64;

    // fused scratch init: cur[] = 0 for this block's rows
    if (t < 64) {
        const int ci = row0 + t;
        if (ci < n) cur[ci] = 0;
    }

    const f32x4 z4 = {0.f, 0.f, 0.f, 0.f};
    f32x4 acc[2][4];
    #pragma unroll
    for (int mi = 0; mi < 2; ++mi)
        #pragma unroll
        for (int ni = 0; ni < 4; ++ni) acc[mi][ni] = z4;

    for (int ph = 0; ph < 2; ++ph) {
        const int k0 = ph * 128;
        if (ph) __syncthreads();

        // ---- stage A: 64 rows x 128 k (bf16, swizzled), 4 iters ----
        #pragma unroll
        for (int i = 0; i < 4; ++i) {
            const int g = i * 256 + t;
            const int r = g >> 4;            // 0..63
            const int c = g & 15;            // 16 chunks of 8
            const int gr = row0 + r;
            float4 v0 = make_float4(0.f,0.f,0.f,0.f), v1 = v0;
            if (gr < n) {
                v0 = *(const float4*)&feats[(size_t)gr * IN_DIM + k0 + c * 8];
                v1 = *(const float4*)&feats[(size_t)gr * IN_DIM + k0 + c * 8 + 4];
            }
            bf16x8 pk;
            pk[0]=(short)f2bf(v0.x); pk[1]=(short)f2bf(v0.y);
            pk[2]=(short)f2bf(v0.z); pk[3]=(short)f2bf(v0.w);
            pk[4]=(short)f2bf(v1.x); pk[5]=(short)f2bf(v1.y);
            pk[6]=(short)f2bf(v1.z); pk[7]=(short)f2bf(v1.w);
            const int off = (r * 128 + c * 8) ^ ((r & 7) << 3);
            *(bf16x8*)&A_s[off] = pk;
        }
        // ---- stage W: 128 outcols x 128 k (bf16, swizzled), 8 iters ----
        #pragma unroll
        for (int i = 0; i < 8; ++i) {
            const int g = i * 256 + t;
            const int r = g >> 4;            // 0..127
            const int c = g & 15;
            const float4 v0 = *(const float4*)&W[(size_t)r * IN_DIM + k0 + c * 8];
            const float4 v1 = *(const float4*)&W[(size_t)r * IN_DIM + k0 + c * 8 + 4];
            bf16x8 pk;
            pk[0]=(short)f2bf(v0.x); pk[1]=(short)f2bf(v0.y);
            pk[2]=(short)f2bf(v0.z); pk[3]=(short)f2bf(v0.w);
            pk[4]=(short)f2bf(v1.x); pk[5]=(short)f2bf(v1.y);
            pk[6]=(short)f2bf(v1.z); pk[7]=(short)f2bf(v1.w);
            const int off = (r * 128 + c * 8) ^ ((r & 7) << 3);
            *(bf16x8*)&W_s[off] = pk;
        }
        __syncthreads();

        // ---- compute: 4 K-steps of 32 ----
        #pragma unroll
        for (int ks = 0; ks < 4; ++ks) {
            const int kf = ks * 32 + (lane >> 4) * 8;
            bf16x8 af[2], wf[4];
            #pragma unroll
            for (int mi = 0; mi < 2; ++mi) {
                const int row = wr * 32 + mi * 16 + (lane & 15);
                const int off = (row * 128 + kf) ^ ((row & 7) << 3);
                af[mi] = *(const bf16x8*)&A_s[off];
            }
            #pragma unroll
            for (int ni = 0; ni < 4; ++ni) {
                const int col = wc * 64 + ni * 16 + (lane & 15);
                const int off = (col * 128 + kf) ^ ((col & 7) << 3);
                wf[ni] = *(const bf16x8*)&W_s[off];
            }
            #pragma unroll
            for (int mi = 0; mi < 2; ++mi)
                #pragma unroll
                for (int ni = 0; ni < 4; ++ni)
                    acc[mi][ni] = __builtin_amdgcn_mfma_f32_16x16x32_bf16(
                        af[mi], wf[ni], acc[mi][ni], 0, 0, 0);
        }
    }

    // ---- epilogue ----
    float bcol[4], avd[4], avs[4];
    #pragma unroll
    for (int ni = 0; ni < 4; ++ni) {
        const int col = wc * 64 + ni * 16 + (lane & 15);
        bcol[ni] = bias[col];
        avd[ni]  = a[col];
        avs[ni]  = a[OUT_DIM + col];
    }

    __syncthreads();   // all MFMA LDS reads done before A_s reuse

    // acc -> A_s (64 x 136 stride, unswizzled) + fused score partials
    #pragma unroll
    for (int mi = 0; mi < 2; ++mi) {
        #pragma unroll
        for (int j = 0; j < 4; ++j) {
            const int rib = wr * 32 + mi * 16 + (lane >> 4) * 4 + j;
            float pd = 0.f, ps = 0.f;
            #pragma unroll
            for (int ni = 0; ni < 4; ++ni) {
                const float v = acc[mi][ni][j] + bcol[ni];
                A_s[rib * 136 + wc * 64 + ni * 16 + (lane & 15)] = f2bf(v);
                pd = fmaf(v, avd[ni], pd);
                ps = fmaf(v, avs[ni], ps);
            }
            pd += __shfl_xor(pd, 1); ps += __shfl_xor(ps, 1);
            pd += __shfl_xor(pd, 2); ps += __shfl_xor(ps, 2);
            pd += __shfl_xor(pd, 4); ps += __shfl_xor(ps, 4);
            pd += __shfl_xor(pd, 8); ps += __shfl_xor(ps, 8);
            if ((lane & 15) == 0) { sd_l[wc][rib] = pd; ss_l[wc][rib] = ps; }
        }
    }
    __syncthreads();

    // coalesced emb store: 64 rows x 16 chunks of 8 bf16, 4 iters
    #pragma unroll
    for (int i = 0; i < 4; ++i) {
        const int g = i * 256 + t;
        const int r = g >> 4;
        const int c8 = g & 15;
        const int gr = row0 + r;
        if (gr < n) {
            const bf16x8 v = *(const bf16x8*)&A_s[r * 136 + c8 * 8];
            *(bf16x8*)&emb_bf[(size_t)gr * OUT_DIM + c8 * 8] = v;
        }
    }
    if (t < 64) {
        const int row = row0 + t;
        if (row < n) {
            s_dst[row] = sd_l[0][t] + sd_l[1][t];
            s_src[row] = ss_l[0][t] + ss_l[1][t];
        }
    }
}

// ---------------------------------------------------------------------------
// Kernel 2: unconditional scatter of ALL edges into per-dst buckets.
// (No needed[] filter: per-dst content identical; un-needed buckets are
// simply never read. Kills flag_kernel + needed init + 1.65M random reads.)
// ---------------------------------------------------------------------------
__global__ __launch_bounds__(256) void scatter_kernel(
    const int* __restrict__ edges, int* __restrict__ cur,
    const float* __restrict__ s_dst, const float* __restrict__ s_src,
    int2* __restrict__ ew, int E)
{
    const int e = blockIdx.x * blockDim.x + threadIdx.x;
    if (e >= E) return;
    const int2 ed = reinterpret_cast<const int2*>(edges)[e];
    const float x = s_dst[ed.x] + s_src[ed.y];
    const float w = __expf(x >= 0.f ? x : SLOPE * x);
    const int p = atomicAdd(&cur[ed.x], 1);
    if (p < CAP)
        ew[(size_t)ed.x * CAP + p] = make_int2(ed.y, __float_as_int(w));
}

// ---------------------------------------------------------------------------
// Kernel 3: fused aggregate + output. One wave per output row.
// ---------------------------------------------------------------------------
__global__ __launch_bounds__(256) void agg_out_kernel(
    const int* __restrict__ node_idx, const int* __restrict__ cur,
    const int2* __restrict__ ew, const unsigned short* __restrict__ emb_bf,
    float* __restrict__ out, int nb)
{
    const int w    = (int)((blockIdx.x * blockDim.x + threadIdx.x) >> 6);
    const int lane = threadIdx.x & 63;
    if (w >= nb) return;

    const int dst = node_idx[w];
    int m = cur[dst];
    if (m > CAP) m = CAP;
    const int2* __restrict__ bucket = ew + (size_t)dst * CAP;

    float accx = 0.f, accy = 0.f, den = 0.f;

    for (int base = 0; base < m; base += 64) {
        const int rem = min(64, m - base);
        int   src = 0;
        float wt  = 0.f;
        if (lane < rem) {
            const int2 q = bucket[base + lane];
            src = q.x;
            wt  = __int_as_float(q.y);
        }
        int i = 0;
        for (; i + 4 <= rem; i += 4) {
            const int   s0 = __shfl(src, i),     s1 = __shfl(src, i + 1);
            const int   s2 = __shfl(src, i + 2), s3 = __shfl(src, i + 3);
            const float w0 = __shfl(wt, i),      w1 = __shfl(wt, i + 1);
            const float w2 = __shfl(wt, i + 2),  w3 = __shfl(wt, i + 3);
            const unsigned b0 = *(const unsigned*)&emb_bf[(size_t)s0 * OUT_DIM + 2 * lane];
            const unsigned b1 = *(const unsigned*)&emb_bf[(size_t)s1 * OUT_DIM + 2 * lane];
            const unsigned b2 = *(const unsigned*)&emb_bf[(size_t)s2 * OUT_DIM + 2 * lane];
            const unsigned b3 = *(const unsigned*)&emb_bf[(size_t)s3 * OUT_DIM + 2 * lane];
            den += (w0 + w1) + (w2 + w3);
            accx = fmaf(w0, __int_as_float((int)(b0 << 16)), accx);
            accy = fmaf(w0, __int_as_float((int)(b0 & 0xFFFF0000u)), accy);
            accx = fmaf(w1, __int_as_float((int)(b1 << 16)), accx);
            accy = fmaf(w1, __int_as_float((int)(b1 & 0xFFFF0000u)), accy);
            accx = fmaf(w2, __int_as_float((int)(b2 << 16)), accx);
            accy = fmaf(w2, __int_as_float((int)(b2 & 0xFFFF0000u)), accy);
            accx = fmaf(w3, __int_as_float((int)(b3 << 16)), accx);
            accy = fmaf(w3, __int_as_float((int)(b3 & 0xFFFF0000u)), accy);
        }
        for (; i < rem; ++i) {
            const int   s0 = __shfl(src, i);
            const float w0 = __shfl(wt, i);
            const unsigned b0 = *(const unsigned*)&emb_bf[(size_t)s0 * OUT_DIM + 2 * lane];
            den += w0;
            accx = fmaf(w0, __int_as_float((int)(b0 << 16)), accx);
            accy = fmaf(w0, __int_as_float((int)(b0 & 0xFFFF0000u)), accy);
        }
    }

    const float inv = 1.0f / den;
    float2 o; o.x = accx * inv; o.y = accy * inv;
    *reinterpret_cast<float2*>(&out[(size_t)w * OUT_DIM + 2 * lane]) = o;
}

// ---------------------------------------------------------------------------
extern "C" void kernel_launch(void* const* d_in, const int* in_sizes, int n_in,
                              void* d_out, int out_size, void* d_ws, size_t ws_size,
                              hipStream_t stream)
{
    const float* feats    = (const float*)d_in[0];
    const float* W        = (const float*)d_in[1];
    const float* bias     = (const float*)d_in[2];
    const float* a        = (const float*)d_in[3];
    const int*   edges    = (const int*)d_in[4];
    const int*   node_idx = (const int*)d_in[5];
    float*       out      = (float*)d_out;

    const int n  = in_sizes[0] / IN_DIM;   // 50000
    const int E  = in_sizes[4] / 2;        // 1650000
    const int nb = in_sizes[5];            // 10000

    // Workspace layout (16B-aligned segments):
    char* ws = (char*)d_ws;
    unsigned short* emb_bf = (unsigned short*)ws;
    ws += (size_t)n * OUT_DIM * sizeof(unsigned short);                 // 12.8 MB
    float* s_dst = (float*)ws;  ws += (size_t)(n + 4) * sizeof(float);
    float* s_src = (float*)ws;  ws += (size_t)(n + 4) * sizeof(float);
    int*   cur   = (int*)ws;    ws += (size_t)(n + 4) * sizeof(int);
    int2*  ew    = (int2*)ws;   ws += (size_t)n * CAP * sizeof(int2);   // 51.2 MB

    gemm_mfma_kernel<<<(n + 63) / 64, 256, 0, stream>>>(
        feats, W, bias, a, emb_bf, s_dst, s_src, cur, n);
    scatter_kernel  <<<(E + 255) / 256, 256, 0, stream>>>(edges, cur, s_dst, s_src, ew, E);
    agg_out_kernel  <<<(nb + 3) / 4, 256, 0, stream>>>(node_idx, cur, ew, emb_bf, out, nb);
}

// Round 9
// 65.817 us; speedup vs baseline: 1.9822x; 1.9822x over previous
//
#include <hip/hip_runtime.h>

#define IN_DIM 256
#define OUT_DIM 128
#define SLOPE 0.1f
#define CAP 128   // per-dst bucket capacity; filtered degree ~ Poisson(33), max ~70

typedef short bf16x8 __attribute__((ext_vector_type(8)));
typedef float f32x4  __attribute__((ext_vector_type(4)));

__device__ __forceinline__ unsigned short f2bf(float f) {
    unsigned u = __builtin_bit_cast(unsigned, f);
    return (unsigned short)((u + 0x7FFFu + ((u >> 16) & 1u)) >> 16);   // RNE
}

// ---------------------------------------------------------------------------
// Kernel 1: emb = feats @ W^T + b via bf16 MFMA. BM=64 tile (782 blocks,
// 3 blocks/CU balanced). Fused: s_dst/s_src scores; needed[]/cur[] init.
// Epilogue: acc -> LDS (stride 136) -> coalesced 16B bf16 stores.
// ---------------------------------------------------------------------------
__global__ __launch_bounds__(256) void gemm_mfma_kernel(
    const float* __restrict__ feats, const float* __restrict__ W,
    const float* __restrict__ bias, const float* __restrict__ a,
    unsigned short* __restrict__ emb_bf, float* __restrict__ s_dst,
    float* __restrict__ s_src, int* __restrict__ needed,
    int* __restrict__ cur, int n)
{
    __shared__ __align__(16) unsigned short A_s[64 * 136];
    __shared__ __align__(16) unsigned short W_s[128 * 128];
    __shared__ float sd_l[2][64];
    __shared__ float ss_l[2][64];

    const int t    = threadIdx.x;
    const int lane = t & 63;
    const int wid  = t >> 6;
    const int wr   = wid >> 1;          // 0..1 : 32-row half
    const int wc   = wid & 1;           // 0..1 : 64-col half
    const int row0 = blockIdx.x * 64;

    // fused scratch init for this block's rows
    if (t < 64) {
        const int ci = row0 + t;
        if (ci < n) { needed[ci] = 0; cur[ci] = 0; }
    }

    const f32x4 z4 = {0.f, 0.f, 0.f, 0.f};
    f32x4 acc[2][4];
    #pragma unroll
    for (int mi = 0; mi < 2; ++mi)
        #pragma unroll
        for (int ni = 0; ni < 4; ++ni) acc[mi][ni] = z4;

    for (int ph = 0; ph < 2; ++ph) {
        const int k0 = ph * 128;
        if (ph) __syncthreads();

        // ---- stage A: 64 rows x 128 k (bf16, swizzled), 4 iters ----
        #pragma unroll
        for (int i = 0; i < 4; ++i) {
            const int g = i * 256 + t;
            const int r = g >> 4;
            const int c = g & 15;
            const int gr = row0 + r;
            float4 v0 = make_float4(0.f,0.f,0.f,0.f), v1 = v0;
            if (gr < n) {
                v0 = *(const float4*)&feats[(size_t)gr * IN_DIM + k0 + c * 8];
                v1 = *(const float4*)&feats[(size_t)gr * IN_DIM + k0 + c * 8 + 4];
            }
            bf16x8 pk;
            pk[0]=(short)f2bf(v0.x); pk[1]=(short)f2bf(v0.y);
            pk[2]=(short)f2bf(v0.z); pk[3]=(short)f2bf(v0.w);
            pk[4]=(short)f2bf(v1.x); pk[5]=(short)f2bf(v1.y);
            pk[6]=(short)f2bf(v1.z); pk[7]=(short)f2bf(v1.w);
            const int off = (r * 128 + c * 8) ^ ((r & 7) << 3);
            *(bf16x8*)&A_s[off] = pk;
        }
        // ---- stage W: 128 outcols x 128 k (bf16, swizzled), 8 iters ----
        #pragma unroll
        for (int i = 0; i < 8; ++i) {
            const int g = i * 256 + t;
            const int r = g >> 4;
            const int c = g & 15;
            const float4 v0 = *(const float4*)&W[(size_t)r * IN_DIM + k0 + c * 8];
            const float4 v1 = *(const float4*)&W[(size_t)r * IN_DIM + k0 + c * 8 + 4];
            bf16x8 pk;
            pk[0]=(short)f2bf(v0.x); pk[1]=(short)f2bf(v0.y);
            pk[2]=(short)f2bf(v0.z); pk[3]=(short)f2bf(v0.w);
            pk[4]=(short)f2bf(v1.x); pk[5]=(short)f2bf(v1.y);
            pk[6]=(short)f2bf(v1.z); pk[7]=(short)f2bf(v1.w);
            const int off = (r * 128 + c * 8) ^ ((r & 7) << 3);
            *(bf16x8*)&W_s[off] = pk;
        }
        __syncthreads();

        // ---- compute: 4 K-steps of 32 ----
        #pragma unroll
        for (int ks = 0; ks < 4; ++ks) {
            const int kf = ks * 32 + (lane >> 4) * 8;
            bf16x8 af[2], wf[4];
            #pragma unroll
            for (int mi = 0; mi < 2; ++mi) {
                const int row = wr * 32 + mi * 16 + (lane & 15);
                const int off = (row * 128 + kf) ^ ((row & 7) << 3);
                af[mi] = *(const bf16x8*)&A_s[off];
            }
            #pragma unroll
            for (int ni = 0; ni < 4; ++ni) {
                const int col = wc * 64 + ni * 16 + (lane & 15);
                const int off = (col * 128 + kf) ^ ((col & 7) << 3);
                wf[ni] = *(const bf16x8*)&W_s[off];
            }
            #pragma unroll
            for (int mi = 0; mi < 2; ++mi)
                #pragma unroll
                for (int ni = 0; ni < 4; ++ni)
                    acc[mi][ni] = __builtin_amdgcn_mfma_f32_16x16x32_bf16(
                        af[mi], wf[ni], acc[mi][ni], 0, 0, 0);
        }
    }

    // ---- epilogue ----
    float bcol[4], avd[4], avs[4];
    #pragma unroll
    for (int ni = 0; ni < 4; ++ni) {
        const int col = wc * 64 + ni * 16 + (lane & 15);
        bcol[ni] = bias[col];
        avd[ni]  = a[col];
        avs[ni]  = a[OUT_DIM + col];
    }

    __syncthreads();   // MFMA LDS reads done before A_s reuse

    #pragma unroll
    for (int mi = 0; mi < 2; ++mi) {
        #pragma unroll
        for (int j = 0; j < 4; ++j) {
            const int rib = wr * 32 + mi * 16 + (lane >> 4) * 4 + j;
            float pd = 0.f, ps = 0.f;
            #pragma unroll
            for (int ni = 0; ni < 4; ++ni) {
                const float v = acc[mi][ni][j] + bcol[ni];
                A_s[rib * 136 + wc * 64 + ni * 16 + (lane & 15)] = f2bf(v);
                pd = fmaf(v, avd[ni], pd);
                ps = fmaf(v, avs[ni], ps);
            }
            pd += __shfl_xor(pd, 1); ps += __shfl_xor(ps, 1);
            pd += __shfl_xor(pd, 2); ps += __shfl_xor(ps, 2);
            pd += __shfl_xor(pd, 4); ps += __shfl_xor(ps, 4);
            pd += __shfl_xor(pd, 8); ps += __shfl_xor(ps, 8);
            if ((lane & 15) == 0) { sd_l[wc][rib] = pd; ss_l[wc][rib] = ps; }
        }
    }
    __syncthreads();

    // coalesced emb store: 64 rows x 16 chunks of 8 bf16
    #pragma unroll
    for (int i = 0; i < 4; ++i) {
        const int g = i * 256 + t;
        const int r = g >> 4;
        const int c8 = g & 15;
        const int gr = row0 + r;
        if (gr < n) {
            const bf16x8 v = *(const bf16x8*)&A_s[r * 136 + c8 * 8];
            *(bf16x8*)&emb_bf[(size_t)gr * OUT_DIM + c8 * 8] = v;
        }
    }
    if (t < 64) {
        const int row = row0 + t;
        if (row < n) {
            s_dst[row] = sd_l[0][t] + sd_l[1][t];
            s_src[row] = ss_l[0][t] + ss_l[1][t];
        }
    }
}

// ---------------------------------------------------------------------------
// Kernel 2: mark needed destinations (plain store; idempotent)
// ---------------------------------------------------------------------------
__global__ void flag_kernel(const int* __restrict__ node_idx,
                            int* __restrict__ needed, int nb)
{
    const int i = blockIdx.x * blockDim.x + threadIdx.x;
    if (i < nb) needed[node_idx[i]] = 1;
}

// ---------------------------------------------------------------------------
// Kernel 3: needed-filtered scatter into per-dst buckets.
// Filter suppresses ~86MB of write-allocate traffic + 1.35M atomics (R8 lesson).
// ---------------------------------------------------------------------------
__global__ __launch_bounds__(256) void scatter_kernel(
    const int* __restrict__ edges, const int* __restrict__ needed,
    int* __restrict__ cur, const float* __restrict__ s_dst,
    const float* __restrict__ s_src, int2* __restrict__ ew, int E)
{
    const int e = blockIdx.x * blockDim.x + threadIdx.x;
    if (e >= E) return;
    const int2 ed = reinterpret_cast<const int2*>(edges)[e];
    if (needed[ed.x]) {
        const float x = s_dst[ed.x] + s_src[ed.y];
        const float w = __expf(x >= 0.f ? x : SLOPE * x);
        const int p = atomicAdd(&cur[ed.x], 1);
        if (p < CAP)
            ew[(size_t)ed.x * CAP + p] = make_int2(ed.y, __float_as_int(w));
    }
}

// ---------------------------------------------------------------------------
// Kernel 4: fused aggregate + output. One wave per output row.
// ---------------------------------------------------------------------------
__global__ __launch_bounds__(256) void agg_out_kernel(
    const int* __restrict__ node_idx, const int* __restrict__ cur,
    const int2* __restrict__ ew, const unsigned short* __restrict__ emb_bf,
    float* __restrict__ out, int nb)
{
    const int w    = (int)((blockIdx.x * blockDim.x + threadIdx.x) >> 6);
    const int lane = threadIdx.x & 63;
    if (w >= nb) return;

    const int dst = node_idx[w];
    int m = cur[dst];
    if (m > CAP) m = CAP;
    const int2* __restrict__ bucket = ew + (size_t)dst * CAP;

    float accx = 0.f, accy = 0.f, den = 0.f;

    for (int base = 0; base < m; base += 64) {
        const int rem = min(64, m - base);
        int   src = 0;
        float wt  = 0.f;
        if (lane < rem) {
            const int2 q = bucket[base + lane];
            src = q.x;
            wt  = __int_as_float(q.y);
        }
        int i = 0;
        for (; i + 4 <= rem; i += 4) {
            const int   s0 = __shfl(src, i),     s1 = __shfl(src, i + 1);
            const int   s2 = __shfl(src, i + 2), s3 = __shfl(src, i + 3);
            const float w0 = __shfl(wt, i),      w1 = __shfl(wt, i + 1);
            const float w2 = __shfl(wt, i + 2),  w3 = __shfl(wt, i + 3);
            const unsigned b0 = *(const unsigned*)&emb_bf[(size_t)s0 * OUT_DIM + 2 * lane];
            const unsigned b1 = *(const unsigned*)&emb_bf[(size_t)s1 * OUT_DIM + 2 * lane];
            const unsigned b2 = *(const unsigned*)&emb_bf[(size_t)s2 * OUT_DIM + 2 * lane];
            const unsigned b3 = *(const unsigned*)&emb_bf[(size_t)s3 * OUT_DIM + 2 * lane];
            den += (w0 + w1) + (w2 + w3);
            accx = fmaf(w0, __int_as_float((int)(b0 << 16)), accx);
            accy = fmaf(w0, __int_as_float((int)(b0 & 0xFFFF0000u)), accy);
            accx = fmaf(w1, __int_as_float((int)(b1 << 16)), accx);
            accy = fmaf(w1, __int_as_float((int)(b1 & 0xFFFF0000u)), accy);
            accx = fmaf(w2, __int_as_float((int)(b2 << 16)), accx);
            accy = fmaf(w2, __int_as_float((int)(b2 & 0xFFFF0000u)), accy);
            accx = fmaf(w3, __int_as_float((int)(b3 << 16)), accx);
            accy = fmaf(w3, __int_as_float((int)(b3 & 0xFFFF0000u)), accy);
        }
        for (; i < rem; ++i) {
            const int   s0 = __shfl(src, i);
            const float w0 = __shfl(wt, i);
            const unsigned b0 = *(const unsigned*)&emb_bf[(size_t)s0 * OUT_DIM + 2 * lane];
            den += w0;
            accx = fmaf(w0, __int_as_float((int)(b0 << 16)), accx);
            accy = fmaf(w0, __int_as_float((int)(b0 & 0xFFFF0000u)), accy);
        }
    }

    const float inv = 1.0f / den;
    float2 o; o.x = accx * inv; o.y = accy * inv;
    *reinterpret_cast<float2*>(&out[(size_t)w * OUT_DIM + 2 * lane]) = o;
}

// ---------------------------------------------------------------------------
extern "C" void kernel_launch(void* const* d_in, const int* in_sizes, int n_in,
                              void* d_out, int out_size, void* d_ws, size_t ws_size,
                              hipStream_t stream)
{
    const float* feats    = (const float*)d_in[0];
    const float* W        = (const float*)d_in[1];
    const float* bias     = (const float*)d_in[2];
    const float* a        = (const float*)d_in[3];
    const int*   edges    = (const int*)d_in[4];
    const int*   node_idx = (const int*)d_in[5];
    float*       out      = (float*)d_out;

    const int n  = in_sizes[0] / IN_DIM;   // 50000
    const int E  = in_sizes[4] / 2;        // 1650000
    const int nb = in_sizes[5];            // 10000

    // Workspace layout (16B-aligned segments):
    char* ws = (char*)d_ws;
    unsigned short* emb_bf = (unsigned short*)ws;
    ws += (size_t)n * OUT_DIM * sizeof(unsigned short);                 // 12.8 MB
    float* s_dst = (float*)ws;  ws += (size_t)(n + 4) * sizeof(float);
    float* s_src = (float*)ws;  ws += (size_t)(n + 4) * sizeof(float);
    int*   needed= (int*)ws;    ws += (size_t)(n + 4) * sizeof(int);
    int*   cur   = (int*)ws;    ws += (size_t)(n + 4) * sizeof(int);
    int2*  ew    = (int2*)ws;   ws += (size_t)n * CAP * sizeof(int2);   // 51.2 MB

    gemm_mfma_kernel<<<(n + 63) / 64, 256, 0, stream>>>(
        feats, W, bias, a, emb_bf, s_dst, s_src, needed, cur, n);
    flag_kernel     <<<(nb + 255) / 256, 256, 0, stream>>>(node_idx, needed, nb);
    scatter_kernel  <<<(E + 255) / 256, 256, 0, stream>>>(edges, needed, cur, s_dst, s_src, ew, E);
    agg_out_kernel  <<<(nb + 3) / 4, 256, 0, stream>>>(node_idx, cur, ew, emb_bf, out, nb);
}

// Round 10
// 65.616 us; speedup vs baseline: 1.9882x; 1.0031x over previous
//
#include <hip/hip_runtime.h>

#define IN_DIM 256
#define OUT_DIM 128
#define SLOPE 0.1f
#define CAP 128   // per-dst bucket capacity; filtered degree ~ Poisson(33), max ~70

typedef short bf16x8 __attribute__((ext_vector_type(8)));
typedef float f32x4  __attribute__((ext_vector_type(4)));

__device__ __forceinline__ unsigned short f2bf(float f) {
    unsigned u = __builtin_bit_cast(unsigned, f);
    return (unsigned short)((u + 0x7FFFu + ((u >> 16) & 1u)) >> 16);   // RNE
}

// ---------------------------------------------------------------------------
// Kernel 1: emb = feats @ W^T + b via bf16 MFMA. BM=128 tile (391 blocks) —
// round-7-proven config. Fused: s_dst/s_src scores; needed[]/cur[] init;
// emb stored bf16.
// ---------------------------------------------------------------------------
__global__ __launch_bounds__(256) void gemm_mfma_kernel(
    const float* __restrict__ feats, const float* __restrict__ W,
    const float* __restrict__ bias, const float* __restrict__ a,
    unsigned short* __restrict__ emb_bf, float* __restrict__ s_dst,
    float* __restrict__ s_src, int* __restrict__ needed,
    int* __restrict__ cur, int n)
{
    __shared__ __align__(16) unsigned short A_s[128 * 128];
    __shared__ __align__(16) unsigned short W_s[128 * 128];
    __shared__ float sd_l[2][128];
    __shared__ float ss_l[2][128];

    const int t    = threadIdx.x;
    const int lane = t & 63;
    const int wid  = t >> 6;
    const int wr   = wid >> 1;
    const int wc   = wid & 1;
    const int row0 = blockIdx.x * 128;

    // fused scratch init (kernel-boundary ordering protects readers)
    if (t < 128) {
        const int ci = row0 + t;
        if (ci < n) { needed[ci] = 0; cur[ci] = 0; }
    }

    const f32x4 z4 = {0.f, 0.f, 0.f, 0.f};
    f32x4 acc[4][4];
    #pragma unroll
    for (int mi = 0; mi < 4; ++mi)
        #pragma unroll
        for (int ni = 0; ni < 4; ++ni) acc[mi][ni] = z4;

    for (int ph = 0; ph < 2; ++ph) {
        const int k0 = ph * 128;
        if (ph) __syncthreads();

        #pragma unroll
        for (int i = 0; i < 8; ++i) {
            const int g = i * 256 + t;
            const int r = g >> 4;
            const int c = g & 15;
            const int gr = row0 + r;
            float4 v0 = make_float4(0.f,0.f,0.f,0.f), v1 = v0;
            if (gr < n) {
                v0 = *(const float4*)&feats[(size_t)gr * IN_DIM + k0 + c * 8];
                v1 = *(const float4*)&feats[(size_t)gr * IN_DIM + k0 + c * 8 + 4];
            }
            bf16x8 pk;
            pk[0]=(short)f2bf(v0.x); pk[1]=(short)f2bf(v0.y);
            pk[2]=(short)f2bf(v0.z); pk[3]=(short)f2bf(v0.w);
            pk[4]=(short)f2bf(v1.x); pk[5]=(short)f2bf(v1.y);
            pk[6]=(short)f2bf(v1.z); pk[7]=(short)f2bf(v1.w);
            const int off = (r * 128 + c * 8) ^ ((r & 7) << 3);
            *(bf16x8*)&A_s[off] = pk;
        }
        #pragma unroll
        for (int i = 0; i < 8; ++i) {
            const int g = i * 256 + t;
            const int r = g >> 4;
            const int c = g & 15;
            const float4 v0 = *(const float4*)&W[(size_t)r * IN_DIM + k0 + c * 8];
            const float4 v1 = *(const float4*)&W[(size_t)r * IN_DIM + k0 + c * 8 + 4];
            bf16x8 pk;
            pk[0]=(short)f2bf(v0.x); pk[1]=(short)f2bf(v0.y);
            pk[2]=(short)f2bf(v0.z); pk[3]=(short)f2bf(v0.w);
            pk[4]=(short)f2bf(v1.x); pk[5]=(short)f2bf(v1.y);
            pk[6]=(short)f2bf(v1.z); pk[7]=(short)f2bf(v1.w);
            const int off = (r * 128 + c * 8) ^ ((r & 7) << 3);
            *(bf16x8*)&W_s[off] = pk;
        }
        __syncthreads();

        #pragma unroll
        for (int ks = 0; ks < 4; ++ks) {
            const int kf = ks * 32 + (lane >> 4) * 8;
            bf16x8 af[4], wf[4];
            #pragma unroll
            for (int mi = 0; mi < 4; ++mi) {
                const int row = wr * 64 + mi * 16 + (lane & 15);
                const int off = (row * 128 + kf) ^ ((row & 7) << 3);
                af[mi] = *(const bf16x8*)&A_s[off];
            }
            #pragma unroll
            for (int ni = 0; ni < 4; ++ni) {
                const int col = wc * 64 + ni * 16 + (lane & 15);
                const int off = (col * 128 + kf) ^ ((col & 7) << 3);
                wf[ni] = *(const bf16x8*)&W_s[off];
            }
            #pragma unroll
            for (int mi = 0; mi < 4; ++mi)
                #pragma unroll
                for (int ni = 0; ni < 4; ++ni)
                    acc[mi][ni] = __builtin_amdgcn_mfma_f32_16x16x32_bf16(
                        af[mi], wf[ni], acc[mi][ni], 0, 0, 0);
        }
    }

    float bcol[4], avd[4], avs[4];
    #pragma unroll
    for (int ni = 0; ni < 4; ++ni) {
        const int col = wc * 64 + ni * 16 + (lane & 15);
        bcol[ni] = bias[col];
        avd[ni]  = a[col];
        avs[ni]  = a[OUT_DIM + col];
    }

    #pragma unroll
    for (int mi = 0; mi < 4; ++mi) {
        #pragma unroll
        for (int j = 0; j < 4; ++j) {
            const int rib = wr * 64 + mi * 16 + (lane >> 4) * 4 + j;
            const int row = row0 + rib;
            float pd = 0.f, ps = 0.f;
            if (row < n) {
                #pragma unroll
                for (int ni = 0; ni < 4; ++ni) {
                    const float v = acc[mi][ni][j] + bcol[ni];
                    emb_bf[(size_t)row * OUT_DIM + wc * 64 + ni * 16 + (lane & 15)] = f2bf(v);
                    pd = fmaf(v, avd[ni], pd);
                    ps = fmaf(v, avs[ni], ps);
                }
            }
            pd += __shfl_xor(pd, 1); ps += __shfl_xor(ps, 1);
            pd += __shfl_xor(pd, 2); ps += __shfl_xor(ps, 2);
            pd += __shfl_xor(pd, 4); ps += __shfl_xor(ps, 4);
            pd += __shfl_xor(pd, 8); ps += __shfl_xor(ps, 8);
            if ((lane & 15) == 0) { sd_l[wc][rib] = pd; ss_l[wc][rib] = ps; }
        }
    }
    __syncthreads();
    if (t < 128) {
        const int row = row0 + t;
        if (row < n) {
            s_dst[row] = sd_l[0][t] + sd_l[1][t];
            s_src[row] = ss_l[0][t] + ss_l[1][t];
        }
    }
}

// ---------------------------------------------------------------------------
// Kernel 2: mark needed destinations (plain store; idempotent)
// ---------------------------------------------------------------------------
__global__ void flag_kernel(const int* __restrict__ node_idx,
                            int* __restrict__ needed, int nb)
{
    const int i = blockIdx.x * blockDim.x + threadIdx.x;
    if (i < nb) needed[node_idx[i]] = 1;
}

// ---------------------------------------------------------------------------
// Kernel 3: needed-filtered scatter, 2 edges per thread (int4 load).
// ---------------------------------------------------------------------------
__global__ __launch_bounds__(256) void scatter_kernel(
    const int* __restrict__ edges, const int* __restrict__ needed,
    int* __restrict__ cur, const float* __restrict__ s_dst,
    const float* __restrict__ s_src, int2* __restrict__ ew, int E)
{
    const int i = blockIdx.x * blockDim.x + threadIdx.x;   // pair index
    const int e0 = 2 * i;
    if (e0 >= E) return;
    const int4 p = reinterpret_cast<const int4*>(edges)[i];  // (dst0,src0,dst1,src1)

    if (needed[p.x]) {
        const float x = s_dst[p.x] + s_src[p.y];
        const float w = __expf(x >= 0.f ? x : SLOPE * x);
        const int q = atomicAdd(&cur[p.x], 1);
        if (q < CAP)
            ew[(size_t)p.x * CAP + q] = make_int2(p.y, __float_as_int(w));
    }
    if (e0 + 1 < E && needed[p.z]) {
        const float x = s_dst[p.z] + s_src[p.w];
        const float w = __expf(x >= 0.f ? x : SLOPE * x);
        const int q = atomicAdd(&cur[p.z], 1);
        if (q < CAP)
            ew[(size_t)p.z * CAP + q] = make_int2(p.w, __float_as_int(w));
    }
}

// ---------------------------------------------------------------------------
// Kernel 4: fused aggregate + output. One wave per output row; 8-deep
// independent gather unroll (addresses depend only on pre-shuffled src).
// ---------------------------------------------------------------------------
__global__ __launch_bounds__(256) void agg_out_kernel(
    const int* __restrict__ node_idx, const int* __restrict__ cur,
    const int2* __restrict__ ew, const unsigned short* __restrict__ emb_bf,
    float* __restrict__ out, int nb)
{
    const int w    = (int)((blockIdx.x * blockDim.x + threadIdx.x) >> 6);
    const int lane = threadIdx.x & 63;
    if (w >= nb) return;

    const int dst = node_idx[w];
    int m = cur[dst];
    if (m > CAP) m = CAP;
    const int2* __restrict__ bucket = ew + (size_t)dst * CAP;

    float accx = 0.f, accy = 0.f, den = 0.f;

    for (int base = 0; base < m; base += 64) {
        const int rem = min(64, m - base);
        int   src = 0;
        float wt  = 0.f;
        if (lane < rem) {
            const int2 q = bucket[base + lane];
            src = q.x;
            wt  = __int_as_float(q.y);
        }
        int i = 0;
        for (; i + 8 <= rem; i += 8) {
            int   s[8];
            float wv[8];
            unsigned b[8];
            #pragma unroll
            for (int u = 0; u < 8; ++u) {
                s[u]  = __shfl(src, i + u);
                wv[u] = __shfl(wt,  i + u);
            }
            #pragma unroll
            for (int u = 0; u < 8; ++u)
                b[u] = *(const unsigned*)&emb_bf[(size_t)s[u] * OUT_DIM + 2 * lane];
            #pragma unroll
            for (int u = 0; u < 8; ++u) {
                den += wv[u];
                accx = fmaf(wv[u], __int_as_float((int)(b[u] << 16)), accx);
                accy = fmaf(wv[u], __int_as_float((int)(b[u] & 0xFFFF0000u)), accy);
            }
        }
        for (; i < rem; ++i) {
            const int   s0 = __shfl(src, i);
            const float w0 = __shfl(wt, i);
            const unsigned b0 = *(const unsigned*)&emb_bf[(size_t)s0 * OUT_DIM + 2 * lane];
            den += w0;
            accx = fmaf(w0, __int_as_float((int)(b0 << 16)), accx);
            accy = fmaf(w0, __int_as_float((int)(b0 & 0xFFFF0000u)), accy);
        }
    }

    const float inv = 1.0f / den;
    float2 o; o.x = accx * inv; o.y = accy * inv;
    *reinterpret_cast<float2*>(&out[(size_t)w * OUT_DIM + 2 * lane]) = o;
}

// ---------------------------------------------------------------------------
extern "C" void kernel_launch(void* const* d_in, const int* in_sizes, int n_in,
                              void* d_out, int out_size, void* d_ws, size_t ws_size,
                              hipStream_t stream)
{
    const float* feats    = (const float*)d_in[0];
    const float* W        = (const float*)d_in[1];
    const float* bias     = (const float*)d_in[2];
    const float* a        = (const float*)d_in[3];
    const int*   edges    = (const int*)d_in[4];
    const int*   node_idx = (const int*)d_in[5];
    float*       out      = (float*)d_out;

    const int n  = in_sizes[0] / IN_DIM;   // 50000
    const int E  = in_sizes[4] / 2;        // 1650000
    const int nb = in_sizes[5];            // 10000
    const int npair = (E + 1) / 2;

    // Workspace layout (16B-aligned segments):
    char* ws = (char*)d_ws;
    unsigned short* emb_bf = (unsigned short*)ws;
    ws += (size_t)n * OUT_DIM * sizeof(unsigned short);                 // 12.8 MB
    float* s_dst = (float*)ws;  ws += (size_t)(n + 4) * sizeof(float);
    float* s_src = (float*)ws;  ws += (size_t)(n + 4) * sizeof(float);
    int*   needed= (int*)ws;    ws += (size_t)(n + 4) * sizeof(int);
    int*   cur   = (int*)ws;    ws += (size_t)(n + 4) * sizeof(int);
    int2*  ew    = (int2*)ws;   ws += (size_t)n * CAP * sizeof(int2);   // 51.2 MB

    gemm_mfma_kernel<<<(n + 127) / 128, 256, 0, stream>>>(
        feats, W, bias, a, emb_bf, s_dst, s_src, needed, cur, n);
    flag_kernel     <<<(nb + 255) / 256, 256, 0, stream>>>(node_idx, needed, nb);
    scatter_kernel  <<<(npair + 255) / 256, 256, 0, stream>>>(edges, needed, cur, s_dst, s_src, ew, E);
    agg_out_kernel  <<<(nb + 3) / 4, 256, 0, stream>>>(node_idx, cur, ew, emb_bf, out, nb);
}